// Round 8
// baseline (302.570 us; speedup 1.0000x reference)
//
#include <hip/hip_runtime.h>

using short8  = __attribute__((ext_vector_type(8))) short;
using ushort8 = __attribute__((ext_vector_type(8))) unsigned short;
using f32x4   = __attribute__((ext_vector_type(4))) float;

#define T 4096
#define E 1024
#define NB 2

__device__ __forceinline__ unsigned short f2bf(float f) {
    unsigned int u = __builtin_bit_cast(unsigned int, f);
    u = (u + 0x7FFFu + ((u >> 16) & 1u)) >> 16;
    return (unsigned short)u;
}

__device__ __forceinline__ void gld16(const unsigned short* g, unsigned short* l) {
    __builtin_amdgcn_global_load_lds(
        (__attribute__((address_space(1))) void*)g,
        (__attribute__((address_space(3))) void*)l, 16, 0, 0);
}

__device__ __forceinline__ void do_cvt(const float* __restrict__ src,
                                       unsigned short* __restrict__ dst, int blk) {
    size_t i = ((size_t)blk * 256 + threadIdx.x) * 8;
    float4 f0 = *(const float4*)(src + i);
    float4 f1 = *(const float4*)(src + i + 4);
    ushort8 u;
    u[0]=f2bf(f0.x); u[1]=f2bf(f0.y); u[2]=f2bf(f0.z); u[3]=f2bf(f0.w);
    u[4]=f2bf(f1.x); u[5]=f2bf(f1.y); u[6]=f2bf(f1.z); u[7]=f2bf(f1.w);
    *(ushort8*)(dst + i) = u;
}

__device__ __forceinline__ void do_vt(const float* __restrict__ v,
                                      unsigned short* __restrict__ vt, int id,
                                      float (*tile)[65]) {
    int b   = id / (64 * 16);
    int rem = id % (64 * 16);
    int t0  = (rem / 16) * 64;
    int e0  = (rem % 16) * 64;
    int tid = threadIdx.x;
    int r   = tid >> 2;
    int c0  = (tid & 3) * 16;
    const float* src = v + ((size_t)(b * T + t0 + r)) * E + e0 + c0;
    #pragma unroll
    for (int i = 0; i < 4; i++) {
        float4 f = *(const float4*)(src + i * 4);
        tile[r][c0 + i*4 + 0] = f.x;
        tile[r][c0 + i*4 + 1] = f.y;
        tile[r][c0 + i*4 + 2] = f.z;
        tile[r][c0 + i*4 + 3] = f.w;
    }
    __syncthreads();
    int er = tid >> 2;
    #pragma unroll
    for (int ch = 0; ch < 2; ch++) {
        int tl = (tid & 3) * 16 + ch * 8;
        ushort8 u;
        #pragma unroll
        for (int j = 0; j < 8; j++) u[j] = f2bf(tile[tl + j][er]);
        *(ushort8*)(vt + ((size_t)(b * E + e0 + er)) * T + t0 + tl) = u;
    }
}

// fused prep: [0,4096) q | [4096,8192) k | [8192,10240) v-transpose | [10240,10272) zero lsum
__global__ __launch_bounds__(256) void prep(const float* __restrict__ q,
                                            const float* __restrict__ k,
                                            const float* __restrict__ v,
                                            unsigned short* __restrict__ qb,
                                            unsigned short* __restrict__ kb,
                                            unsigned short* __restrict__ vt,
                                            float* __restrict__ lsum) {
    __shared__ float tile[64][65];
    int bid = blockIdx.x;
    if (bid < 4096)        do_cvt(q, qb, bid);
    else if (bid < 8192)   do_cvt(k, kb, bid - 4096);
    else if (bid < 10240)  do_vt(v, vt, bid - 8192, tile);
    else                   lsum[(bid - 10240) * 256 + threadIdx.x] = 0.0f;
}

// fallback pieces (aliased-ws path)
__global__ __launch_bounds__(256) void prologue(const float* __restrict__ q,
                                                const float* __restrict__ k,
                                                unsigned short* __restrict__ qb,
                                                unsigned short* __restrict__ kb,
                                                float* __restrict__ lsum) {
    int bid = blockIdx.x;
    if (bid < 4096)      do_cvt(q, qb, bid);
    else if (bid < 8192) do_cvt(k, kb, bid - 4096);
    else                 lsum[(bid - 8192) * 256 + threadIdx.x] = 0.0f;
}
__global__ __launch_bounds__(256) void v_transpose(const float* __restrict__ v,
                                                   unsigned short* __restrict__ vt) {
    __shared__ float tile[64][65];
    do_vt(v, vt, blockIdx.x, tile);
}

// ---------------------------------------------------------------------------
// Shared core (pass2): 128x128xBK64, 256 threads (4 waves, 2Mx2N).
// NBUF=2, 64 KB LDS -> 2 blocks/CU. HW-verified R2/R4/R7.
// ---------------------------------------------------------------------------
template <int KITERS>
__device__ __forceinline__ void gemm_core64(const unsigned short* Abase, int apitch,
                                            const unsigned short* Bbase, int bpitch,
                                            unsigned short* ldsA, unsigned short* ldsB,
                                            int tid, f32x4 (&acc)[4][4]) {
    constexpr int TILE64 = 128 * 64;         // 8192 ushorts = 16 KB
    const int lane = tid & 63, wave = tid >> 6;
    const int l15 = lane & 15, kq = lane >> 4;
    const int wm = (wave & 1) * 64, wn = (wave >> 1) * 64;

    int goA[4], goB[4], lo[4];
    #pragma unroll
    for (int i = 0; i < 4; i++) {
        int p = i * 256 + tid;
        int r = p >> 3, c = p & 7;
        int sw = c ^ (r & 7);
        goA[i] = r * apitch + sw * 8;
        goB[i] = r * bpitch + sw * 8;
        lo[i] = (i * 256 + wave * 64) * 8;
    }
    int aoff[2][4], boff[2][4];
    #pragma unroll
    for (int mi = 0; mi < 4; mi++) {
        int r = wm + mi * 16 + l15;
        aoff[0][mi] = (r * 8 + (kq ^ (r & 7))) * 8;
        aoff[1][mi] = (r * 8 + ((kq ^ 4) ^ (r & 7))) * 8;
        int rn = wn + mi * 16 + l15;
        boff[0][mi] = (rn * 8 + (kq ^ (rn & 7))) * 8;
        boff[1][mi] = (rn * 8 + ((kq ^ 4) ^ (rn & 7))) * 8;
    }

    #pragma unroll
    for (int i = 0; i < 4; i++) gld16(Abase + goA[i], ldsA + lo[i]);
    #pragma unroll
    for (int i = 0; i < 4; i++) gld16(Bbase + goB[i], ldsB + lo[i]);

    int cbuf = 0;
    for (int kt = 0; kt < KITERS; kt++) {
        int pk = (kt + 1 < KITERS) ? (kt + 1) : 0;
        int ob = cbuf ^ 1;
        asm volatile("s_barrier" ::: "memory");
        #pragma unroll
        for (int i = 0; i < 4; i++) gld16(Abase + goA[i] + pk * 64, ldsA + ob * TILE64 + lo[i]);
        #pragma unroll
        for (int i = 0; i < 4; i++) gld16(Bbase + goB[i] + pk * 64, ldsB + ob * TILE64 + lo[i]);
        asm volatile("s_waitcnt vmcnt(8)" ::: "memory");
        asm volatile("s_barrier" ::: "memory");

        const unsigned short* A = ldsA + cbuf * TILE64;
        const unsigned short* B = ldsB + cbuf * TILE64;
        #pragma unroll
        for (int ks = 0; ks < 2; ks++) {
            short8 af[4], bf[4];
            #pragma unroll
            for (int i = 0; i < 4; i++) {
                af[i] = *(const short8*)(A + aoff[ks][i]);
                bf[i] = *(const short8*)(B + boff[ks][i]);
            }
            #pragma unroll
            for (int mi = 0; mi < 4; mi++)
                #pragma unroll
                for (int ni = 0; ni < 4; ni++)
                    acc[mi][ni] = __builtin_amdgcn_mfma_f32_16x16x32_bf16(af[mi], bf[ni], acc[mi][ni], 0, 0, 0);
        }
        cbuf = ob;
    }
}

// ---------------------------------------------------------------------------
// Pass 1 (persistent): P = exp2(scale*log2e*(Q K^T) - 12), lsum += row sums.
// Grid 512 = exactly 2 blocks/CU. Each block: 4 consecutive nt tiles, same
// gm (A panel reused, L2-hot). Double-buffer pipeline CONTINUES across tile
// boundaries: last K-iter of tile i stages tile i+1's first slab, so the
// epilogue (stores, no LDS) overlaps the next tile's load latency. This
// removes the ~7us/block fixed cost that made 2048-block pass1 = 117us.
// ---------------------------------------------------------------------------
__global__ __launch_bounds__(256, 2) void pass1(const unsigned short* __restrict__ qb,
                                                const unsigned short* __restrict__ kb,
                                                unsigned short* __restrict__ P,
                                                float* __restrict__ lsum) {
    constexpr int TILE64 = 128 * 64;
    __shared__ unsigned short ldsA[2 * TILE64];  // 32 KB
    __shared__ unsigned short ldsB[2 * TILE64];  // 32 KB

    const int bx  = blockIdx.x;
    const int xc  = bx & 7;                  // XCD
    const int sj  = bx >> 3;                 // [0,64)
    const int gm  = xc * 8 + (sj & 7);       // [0,64): b*32+mt
    const int ntb = (sj >> 3) * 4;           // [0,32) step 4: this block's 4 nt
    const int b = gm >> 5, mt = gm & 31;
    const int tid = threadIdx.x;
    const int lane = tid & 63, wave = tid >> 6;
    const int l15 = lane & 15, kq = lane >> 4;
    const int wm = (wave & 1) * 64, wn = (wave >> 1) * 64;
    const int quad = lane >> 4;

    const unsigned short* Ab = qb + ((size_t)b * T + mt * 128) * E;
    const unsigned short* Bb = kb + ((size_t)b * T + ntb * 128) * E;  // 4 panels contiguous

    int goA[4], goB[4], lo[4];
    #pragma unroll
    for (int i = 0; i < 4; i++) {
        int p = i * 256 + tid;
        int r = p >> 3, c = p & 7;
        int sw = c ^ (r & 7);
        goA[i] = r * E + sw * 8;
        goB[i] = r * E + sw * 8;
        lo[i] = (i * 256 + wave * 64) * 8;
    }
    int aoff[2][4], boff[2][4];
    #pragma unroll
    for (int mi = 0; mi < 4; mi++) {
        int r = wm + mi * 16 + l15;
        aoff[0][mi] = (r * 8 + (kq ^ (r & 7))) * 8;
        aoff[1][mi] = (r * 8 + ((kq ^ 4) ^ (r & 7))) * 8;
        int rn = wn + mi * 16 + l15;
        boff[0][mi] = (rn * 8 + (kq ^ (rn & 7))) * 8;
        boff[1][mi] = (rn * 8 + ((kq ^ 4) ^ (rn & 7))) * 8;
    }

    f32x4 acc[4][4];
    #pragma unroll
    for (int i = 0; i < 4; i++)
        #pragma unroll
        for (int jj = 0; jj < 4; jj++) acc[i][jj] = {};

    // prologue: (tile 0, kt 0) -> buffer 0
    #pragma unroll
    for (int i = 0; i < 4; i++) gld16(Ab + goA[i], ldsA + lo[i]);
    #pragma unroll
    for (int i = 0; i < 4; i++) gld16(Bb + goB[i], ldsB + lo[i]);

    const float sl2 = 0.0625f * 1.44269504089f;
    int cbuf = 0;
    for (int it = 0; it < 4; ++it) {
        for (int kt = 0; kt < 16; ++kt) {
            const int ob = cbuf ^ 1;
            asm volatile("s_barrier" ::: "memory");
            int nit = it, nk = kt + 1;
            if (nk == 16) { nk = 0; nit++; }
            if (nit < 4) {   // uniform branch
                const unsigned short* An = Ab + nk * 64;
                const unsigned short* Bn = Bb + (size_t)nit * (128 * E) + nk * 64;
                #pragma unroll
                for (int i = 0; i < 4; i++) gld16(An + goA[i], ldsA + ob * TILE64 + lo[i]);
                #pragma unroll
                for (int i = 0; i < 4; i++) gld16(Bn + goB[i], ldsB + ob * TILE64 + lo[i]);
                // queue: [cur-tile loads(8) | prev epilogue stores | new loads(8)]
                // vmcnt(8) keeps only the new 8 in flight -> cur data + stores drained
                asm volatile("s_waitcnt vmcnt(8)" ::: "memory");
            } else {
                asm volatile("s_waitcnt vmcnt(0)" ::: "memory");
            }
            asm volatile("s_barrier" ::: "memory");

            const unsigned short* A = ldsA + cbuf * TILE64;
            const unsigned short* B = ldsB + cbuf * TILE64;
            #pragma unroll
            for (int ks = 0; ks < 2; ks++) {
                short8 af[4], bf[4];
                #pragma unroll
                for (int i = 0; i < 4; i++) {
                    af[i] = *(const short8*)(A + aoff[ks][i]);
                    bf[i] = *(const short8*)(B + boff[ks][i]);
                }
                #pragma unroll
                for (int mi = 0; mi < 4; mi++)
                    #pragma unroll
                    for (int ni = 0; ni < 4; ni++)
                        acc[mi][ni] = __builtin_amdgcn_mfma_f32_16x16x32_bf16(af[mi], bf[ni], acc[mi][ni], 0, 0, 0);
            }
            cbuf = ob;
        }

        // epilogue for tile it (no LDS; overlaps next tile's in-flight loads)
        const int nt = ntb + it;
        const int col0 = nt * 128 + wn + l15;
        #pragma unroll
        for (int mi = 0; mi < 4; mi++) {
            #pragma unroll
            for (int r = 0; r < 4; r++) {
                int row = mt * 128 + wm + mi * 16 + quad * 4 + r;
                size_t base = ((size_t)b * T + row) * T + col0;
                float rs = 0.0f;
                #pragma unroll
                for (int ni = 0; ni < 4; ni++) {
                    float p = exp2f(acc[mi][ni][r] * sl2 - 12.0f);
                    P[base + ni * 16] = f2bf(p);
                    rs += p;
                }
                rs += __shfl_xor(rs, 1);
                rs += __shfl_xor(rs, 2);
                rs += __shfl_xor(rs, 4);
                rs += __shfl_xor(rs, 8);
                if (l15 == 0) atomicAdd(lsum + b * T + row, rs);
            }
        }
        #pragma unroll
        for (int i = 0; i < 4; i++)
            #pragma unroll
            for (int jj = 0; jj < 4; jj++) acc[i][jj] = {};
    }
}

// Pass 2: O = (P @ V) / l ; B operand = VT [b][e][t]  (unchanged, ~75us)
__global__ __launch_bounds__(256, 2) void pass2(const unsigned short* __restrict__ P,
                                                const unsigned short* __restrict__ vt,
                                                const float* __restrict__ lsum,
                                                float* __restrict__ out) {
    constexpr int TILE64 = 128 * 64;
    __shared__ unsigned short ldsA[2 * TILE64];  // 32 KB
    __shared__ unsigned short ldsB[2 * TILE64];  // 32 KB

    const int bx = blockIdx.x;
    const int xc = bx & 7, j = bx >> 3;      // j in [0,64)
    const int gm = xc * 8 + (j & 7);         // [0,64): b*32+mt
    const int nt = j >> 3;                   // [0,8)
    const int b = gm >> 5, mt = gm & 31;
    const int tid = threadIdx.x;

    f32x4 acc[4][4];
    #pragma unroll
    for (int i = 0; i < 4; i++)
        #pragma unroll
        for (int jj = 0; jj < 4; jj++) acc[i][jj] = {};

    gemm_core64<T / 64>(P + ((size_t)b * T + mt * 128) * T, T,
                        vt + ((size_t)b * E + nt * 128) * T, T,
                        ldsA, ldsB, tid, acc);

    const int lane = tid & 63, wave = tid >> 6;
    const int wm = (wave & 1) * 64, wn = (wave >> 1) * 64;
    const int quad = lane >> 4, l15 = lane & 15;
    const int col0 = nt * 128 + wn + l15;

    #pragma unroll
    for (int mi = 0; mi < 4; mi++) {
        #pragma unroll
        for (int r = 0; r < 4; r++) {
            int row = mt * 128 + wm + mi * 16 + quad * 4 + r;
            float rl = 1.0f / lsum[b * T + row];
            size_t base = ((size_t)b * T + row) * E + col0;
            #pragma unroll
            for (int ni = 0; ni < 4; ni++)
                out[base + ni * 16] = acc[mi][ni][r] * rl;
        }
    }
}

extern "C" void kernel_launch(void* const* d_in, const int* in_sizes, int n_in,
                              void* d_out, int out_size, void* d_ws, size_t ws_size,
                              hipStream_t stream) {
    const float* q = (const float*)d_in[0];
    const float* k = (const float*)d_in[1];
    const float* v = (const float*)d_in[2];
    float* out = (float*)d_out;

    const size_t QK = (size_t)NB * T * E;
    const size_t PSZ = (size_t)NB * T * T;
    float* lsum = (float*)d_ws;
    unsigned short* qbw = (unsigned short*)((char*)d_ws + 32768);
    unsigned short* kbw = qbw + QK;
    unsigned short* Pw  = kbw + QK;

    const size_t full_need = 32768 + (3 * QK + PSZ) * sizeof(unsigned short);

    if (ws_size >= full_need) {
        unsigned short* vtw = Pw + PSZ;
        prep<<<10272, 256, 0, stream>>>(q, k, v, qbw, kbw, vtw, lsum);
        pass1<<<512, 256, 0, stream>>>(qbw, kbw, Pw, lsum);
        pass2<<<512, 256, 0, stream>>>(Pw, vtw, lsum, out);
    } else {
        unsigned short* vtw = qbw;
        prologue<<<8224, 256, 0, stream>>>(q, k, qbw, kbw, lsum);
        pass1<<<512, 256, 0, stream>>>(qbw, kbw, Pw, lsum);
        v_transpose<<<NB * 64 * 16, 256, 0, stream>>>(v, vtw);
        pass2<<<512, 256, 0, stream>>>(Pw, vtw, lsum, out);
    }
}

// Round 9
// 296.624 us; speedup vs baseline: 1.0200x; 1.0200x over previous
//
#include <hip/hip_runtime.h>

using short8  = __attribute__((ext_vector_type(8))) short;
using ushort8 = __attribute__((ext_vector_type(8))) unsigned short;
using f32x4   = __attribute__((ext_vector_type(4))) float;

#define T 4096
#define E 1024
#define NB 2

__device__ __forceinline__ unsigned short f2bf(float f) {
    unsigned int u = __builtin_bit_cast(unsigned int, f);
    u = (u + 0x7FFFu + ((u >> 16) & 1u)) >> 16;
    return (unsigned short)u;
}

__device__ __forceinline__ void gld16(const unsigned short* g, unsigned short* l) {
    __builtin_amdgcn_global_load_lds(
        (__attribute__((address_space(1))) void*)g,
        (__attribute__((address_space(3))) void*)l, 16, 0, 0);
}

__device__ __forceinline__ void do_cvt(const float* __restrict__ src,
                                       unsigned short* __restrict__ dst, int blk) {
    size_t i = ((size_t)blk * 256 + threadIdx.x) * 8;
    float4 f0 = *(const float4*)(src + i);
    float4 f1 = *(const float4*)(src + i + 4);
    ushort8 u;
    u[0]=f2bf(f0.x); u[1]=f2bf(f0.y); u[2]=f2bf(f0.z); u[3]=f2bf(f0.w);
    u[4]=f2bf(f1.x); u[5]=f2bf(f1.y); u[6]=f2bf(f1.z); u[7]=f2bf(f1.w);
    *(ushort8*)(dst + i) = u;
}

__device__ __forceinline__ void do_vt(const float* __restrict__ v,
                                      unsigned short* __restrict__ vt, int id,
                                      float (*tile)[65]) {
    int b   = id / (64 * 16);
    int rem = id % (64 * 16);
    int t0  = (rem / 16) * 64;
    int e0  = (rem % 16) * 64;
    int tid = threadIdx.x;
    int r   = tid >> 2;
    int c0  = (tid & 3) * 16;
    const float* src = v + ((size_t)(b * T + t0 + r)) * E + e0 + c0;
    #pragma unroll
    for (int i = 0; i < 4; i++) {
        float4 f = *(const float4*)(src + i * 4);
        tile[r][c0 + i*4 + 0] = f.x;
        tile[r][c0 + i*4 + 1] = f.y;
        tile[r][c0 + i*4 + 2] = f.z;
        tile[r][c0 + i*4 + 3] = f.w;
    }
    __syncthreads();
    int er = tid >> 2;
    #pragma unroll
    for (int ch = 0; ch < 2; ch++) {
        int tl = (tid & 3) * 16 + ch * 8;
        ushort8 u;
        #pragma unroll
        for (int j = 0; j < 8; j++) u[j] = f2bf(tile[tl + j][er]);
        *(ushort8*)(vt + ((size_t)(b * E + e0 + er)) * T + t0 + tl) = u;
    }
}

// fused prep: [0,4096) q | [4096,8192) k | [8192,10240) v-transpose | [10240,10272) zero lsum
__global__ __launch_bounds__(256) void prep(const float* __restrict__ q,
                                            const float* __restrict__ k,
                                            const float* __restrict__ v,
                                            unsigned short* __restrict__ qb,
                                            unsigned short* __restrict__ kb,
                                            unsigned short* __restrict__ vt,
                                            float* __restrict__ lsum) {
    __shared__ float tile[64][65];
    int bid = blockIdx.x;
    if (bid < 4096)        do_cvt(q, qb, bid);
    else if (bid < 8192)   do_cvt(k, kb, bid - 4096);
    else if (bid < 10240)  do_vt(v, vt, bid - 8192, tile);
    else                   lsum[(bid - 10240) * 256 + threadIdx.x] = 0.0f;
}

// fallback pieces (aliased-ws path)
__global__ __launch_bounds__(256) void prologue(const float* __restrict__ q,
                                                const float* __restrict__ k,
                                                unsigned short* __restrict__ qb,
                                                unsigned short* __restrict__ kb,
                                                float* __restrict__ lsum) {
    int bid = blockIdx.x;
    if (bid < 4096)      do_cvt(q, qb, bid);
    else if (bid < 8192) do_cvt(k, kb, bid - 4096);
    else                 lsum[(bid - 8192) * 256 + threadIdx.x] = 0.0f;
}
__global__ __launch_bounds__(256) void v_transpose(const float* __restrict__ v,
                                                   unsigned short* __restrict__ vt) {
    __shared__ float tile[64][65];
    do_vt(v, vt, blockIdx.x, tile);
}

// ---------------------------------------------------------------------------
// Shared core (pass2): 128x128xBK64, 256 threads (4 waves, 2Mx2N).
// NBUF=2, 64 KB LDS -> 2 blocks/CU. HW-verified R2/R4/R7/R8 (~936 TF as pass2).
// ---------------------------------------------------------------------------
template <int KITERS>
__device__ __forceinline__ void gemm_core64(const unsigned short* Abase, int apitch,
                                            const unsigned short* Bbase, int bpitch,
                                            unsigned short* ldsA, unsigned short* ldsB,
                                            int tid, f32x4 (&acc)[4][4]) {
    constexpr int TILE64 = 128 * 64;         // 8192 ushorts = 16 KB
    const int lane = tid & 63, wave = tid >> 6;
    const int l15 = lane & 15, kq = lane >> 4;
    const int wm = (wave & 1) * 64, wn = (wave >> 1) * 64;

    int goA[4], goB[4], lo[4];
    #pragma unroll
    for (int i = 0; i < 4; i++) {
        int p = i * 256 + tid;
        int r = p >> 3, c = p & 7;
        int sw = c ^ (r & 7);
        goA[i] = r * apitch + sw * 8;
        goB[i] = r * bpitch + sw * 8;
        lo[i] = (i * 256 + wave * 64) * 8;
    }
    int aoff[2][4], boff[2][4];
    #pragma unroll
    for (int mi = 0; mi < 4; mi++) {
        int r = wm + mi * 16 + l15;
        aoff[0][mi] = (r * 8 + (kq ^ (r & 7))) * 8;
        aoff[1][mi] = (r * 8 + ((kq ^ 4) ^ (r & 7))) * 8;
        int rn = wn + mi * 16 + l15;
        boff[0][mi] = (rn * 8 + (kq ^ (rn & 7))) * 8;
        boff[1][mi] = (rn * 8 + ((kq ^ 4) ^ (rn & 7))) * 8;
    }

    #pragma unroll
    for (int i = 0; i < 4; i++) gld16(Abase + goA[i], ldsA + lo[i]);
    #pragma unroll
    for (int i = 0; i < 4; i++) gld16(Bbase + goB[i], ldsB + lo[i]);

    int cbuf = 0;
    for (int kt = 0; kt < KITERS; kt++) {
        int pk = (kt + 1 < KITERS) ? (kt + 1) : 0;
        int ob = cbuf ^ 1;
        asm volatile("s_barrier" ::: "memory");
        #pragma unroll
        for (int i = 0; i < 4; i++) gld16(Abase + goA[i] + pk * 64, ldsA + ob * TILE64 + lo[i]);
        #pragma unroll
        for (int i = 0; i < 4; i++) gld16(Bbase + goB[i] + pk * 64, ldsB + ob * TILE64 + lo[i]);
        asm volatile("s_waitcnt vmcnt(8)" ::: "memory");
        asm volatile("s_barrier" ::: "memory");

        const unsigned short* A = ldsA + cbuf * TILE64;
        const unsigned short* B = ldsB + cbuf * TILE64;
        #pragma unroll
        for (int ks = 0; ks < 2; ks++) {
            short8 af[4], bf[4];
            #pragma unroll
            for (int i = 0; i < 4; i++) {
                af[i] = *(const short8*)(A + aoff[ks][i]);
                bf[i] = *(const short8*)(B + boff[ks][i]);
            }
            #pragma unroll
            for (int mi = 0; mi < 4; mi++)
                #pragma unroll
                for (int ni = 0; ni < 4; ni++)
                    acc[mi][ni] = __builtin_amdgcn_mfma_f32_16x16x32_bf16(af[mi], bf[ni], acc[mi][ni], 0, 0, 0);
        }
        cbuf = ob;
    }
}

// ---------------------------------------------------------------------------
// Pass 1 (persistent, LDS-coalesced epilogue): 512 blocks = 2/CU, 4 nt tiles
// per block, pipeline continues across tile boundaries. Epilogue routes P
// through the just-freed LDS compute buffer (cbuf regions; prefetch targets
// ob) so each thread issues 8 full-cacheline global_store_dwordx4 instead of
// 64 scattered ushort stores -> the vmcnt(8) drain at the next tile gate
// shrinks ~4x in transactions. Quad-XOR col-group swizzle keeps ds_writes
// conflict-free.
// ---------------------------------------------------------------------------
__global__ __launch_bounds__(256, 2) void pass1(const unsigned short* __restrict__ qb,
                                                const unsigned short* __restrict__ kb,
                                                unsigned short* __restrict__ P,
                                                float* __restrict__ lsum) {
    constexpr int TILE64 = 128 * 64;
    __shared__ unsigned short ldsA[2 * TILE64];  // 32 KB
    __shared__ unsigned short ldsB[2 * TILE64];  // 32 KB

    const int bx  = blockIdx.x;
    const int xc  = bx & 7;                  // XCD
    const int sj  = bx >> 3;                 // [0,64)
    const int gm  = xc * 8 + (sj & 7);       // [0,64): b*32+mt
    const int ntb = (sj >> 3) * 4;           // [0,32) step 4
    const int b = gm >> 5, mt = gm & 31;
    const int tid = threadIdx.x;
    const int lane = tid & 63, wave = tid >> 6;
    const int l15 = lane & 15, kq = lane >> 4;
    const int wm = (wave & 1) * 64, wn = (wave >> 1) * 64;
    const int quad = lane >> 4;

    const unsigned short* Ab = qb + ((size_t)b * T + mt * 128) * E;
    const unsigned short* Bb = kb + ((size_t)b * T + ntb * 128) * E;

    int goA[4], goB[4], lo[4];
    #pragma unroll
    for (int i = 0; i < 4; i++) {
        int p = i * 256 + tid;
        int r = p >> 3, c = p & 7;
        int sw = c ^ (r & 7);
        goA[i] = r * E + sw * 8;
        goB[i] = r * E + sw * 8;
        lo[i] = (i * 256 + wave * 64) * 8;
    }
    int aoff[2][4], boff[2][4];
    #pragma unroll
    for (int mi = 0; mi < 4; mi++) {
        int r = wm + mi * 16 + l15;
        aoff[0][mi] = (r * 8 + (kq ^ (r & 7))) * 8;
        aoff[1][mi] = (r * 8 + ((kq ^ 4) ^ (r & 7))) * 8;
        int rn = wn + mi * 16 + l15;
        boff[0][mi] = (rn * 8 + (kq ^ (rn & 7))) * 8;
        boff[1][mi] = (rn * 8 + ((kq ^ 4) ^ (rn & 7))) * 8;
    }

    f32x4 acc[4][4];
    #pragma unroll
    for (int i = 0; i < 4; i++)
        #pragma unroll
        for (int jj = 0; jj < 4; jj++) acc[i][jj] = {};

    // prologue: (tile 0, kt 0) -> buffer 0
    #pragma unroll
    for (int i = 0; i < 4; i++) gld16(Ab + goA[i], ldsA + lo[i]);
    #pragma unroll
    for (int i = 0; i < 4; i++) gld16(Bb + goB[i], ldsB + lo[i]);

    const float sl2 = 0.0625f * 1.44269504089f;
    int cbuf = 0;
    for (int it = 0; it < 4; ++it) {
        for (int kt = 0; kt < 16; ++kt) {
            const int ob = cbuf ^ 1;
            asm volatile("s_barrier" ::: "memory");
            int nit = it, nk = kt + 1;
            if (nk == 16) { nk = 0; nit++; }
            if (nit < 4) {   // uniform branch
                const unsigned short* An = Ab + nk * 64;
                const unsigned short* Bn = Bb + (size_t)nit * (128 * E) + nk * 64;
                #pragma unroll
                for (int i = 0; i < 4; i++) gld16(An + goA[i], ldsA + ob * TILE64 + lo[i]);
                #pragma unroll
                for (int i = 0; i < 4; i++) gld16(Bn + goB[i], ldsB + ob * TILE64 + lo[i]);
                asm volatile("s_waitcnt vmcnt(8)" ::: "memory");
            } else {
                asm volatile("s_waitcnt vmcnt(0)" ::: "memory");
            }
            asm volatile("s_barrier" ::: "memory");

            const unsigned short* A = ldsA + cbuf * TILE64;
            const unsigned short* B = ldsB + cbuf * TILE64;
            #pragma unroll
            for (int ks = 0; ks < 2; ks++) {
                short8 af[4], bf[4];
                #pragma unroll
                for (int i = 0; i < 4; i++) {
                    af[i] = *(const short8*)(A + aoff[ks][i]);
                    bf[i] = *(const short8*)(B + boff[ks][i]);
                }
                #pragma unroll
                for (int mi = 0; mi < 4; mi++)
                    #pragma unroll
                    for (int ni = 0; ni < 4; ni++)
                        acc[mi][ni] = __builtin_amdgcn_mfma_f32_16x16x32_bf16(af[mi], bf[ni], acc[mi][ni], 0, 0, 0);
            }
            cbuf = ob;
        }
        // NOTE: after the kt-loop, cbuf points at the buffer the NEXT tile's
        // k=0 data is landing in (ob of the last iter); the just-consumed
        // buffer is cbuf^1. Scratch = (cbuf^1) regions of ldsA+ldsB.
        const int sb = cbuf ^ 1;
        unsigned short* scr = (wave < 2 ? ldsA : ldsB) + sb * TILE64 + (wave & 1) * 4096;

        const int nt = ntb + it;
        __syncthreads();   // all waves done MFMA-reading buffer sb
        // write phase: p -> bf16 into scratch (quad-XOR col-group swizzle),
        // row-sum via shfl + one atomic per row (unchanged)
        #pragma unroll
        for (int mi = 0; mi < 4; mi++) {
            #pragma unroll
            for (int r = 0; r < 4; r++) {
                int lrow = mi * 16 + quad * 4 + r;          // [0,64)
                float rs = 0.0f;
                #pragma unroll
                for (int ni = 0; ni < 4; ni++) {
                    float p = exp2f(acc[mi][ni][r] * sl2 - 12.0f);
                    scr[lrow * 64 + l15 + ((ni ^ quad) << 4)] = f2bf(p);
                    rs += p;
                }
                rs += __shfl_xor(rs, 1);
                rs += __shfl_xor(rs, 2);
                rs += __shfl_xor(rs, 4);
                rs += __shfl_xor(rs, 8);
                if (l15 == 0) {
                    int row = mt * 128 + wm + lrow;
                    atomicAdd(lsum + b * T + row, rs);
                }
            }
        }
        __syncthreads();   // writes visible (and lgkm drained)
        // read phase: 8x ds_read_b128 -> 8x global_store_dwordx4 (coalesced)
        {
            const int c = lane & 7;          // chunk 0..7 (8 cols each)
            const int g = c >> 1;            // 16-col group
            #pragma unroll
            for (int ii = 0; ii < 8; ii++) {
                int rr = (lane >> 3) + ii * 8;               // [0,64)
                int cp = (c & 1) + ((g ^ ((rr >> 2) & 3)) << 1);
                ushort8 v = *(const ushort8*)(scr + rr * 64 + cp * 8);
                size_t gaddr = ((size_t)b * T + mt * 128 + wm + rr) * T
                             + (size_t)nt * 128 + wn + c * 8;
                *(ushort8*)(P + gaddr) = v;
            }
        }
        #pragma unroll
        for (int i = 0; i < 4; i++)
            #pragma unroll
            for (int jj = 0; jj < 4; jj++) acc[i][jj] = {};
    }
}

// Pass 2: O = (P @ V) / l ; B operand = VT [b][e][t]  (unchanged)
__global__ __launch_bounds__(256, 2) void pass2(const unsigned short* __restrict__ P,
                                                const unsigned short* __restrict__ vt,
                                                const float* __restrict__ lsum,
                                                float* __restrict__ out) {
    constexpr int TILE64 = 128 * 64;
    __shared__ unsigned short ldsA[2 * TILE64];  // 32 KB
    __shared__ unsigned short ldsB[2 * TILE64];  // 32 KB

    const int bx = blockIdx.x;
    const int xc = bx & 7, j = bx >> 3;      // j in [0,64)
    const int gm = xc * 8 + (j & 7);         // [0,64): b*32+mt
    const int nt = j >> 3;                   // [0,8)
    const int b = gm >> 5, mt = gm & 31;
    const int tid = threadIdx.x;

    f32x4 acc[4][4];
    #pragma unroll
    for (int i = 0; i < 4; i++)
        #pragma unroll
        for (int jj = 0; jj < 4; jj++) acc[i][jj] = {};

    gemm_core64<T / 64>(P + ((size_t)b * T + mt * 128) * T, T,
                        vt + ((size_t)b * E + nt * 128) * T, T,
                        ldsA, ldsB, tid, acc);

    const int lane = tid & 63, wave = tid >> 6;
    const int wm = (wave & 1) * 64, wn = (wave >> 1) * 64;
    const int quad = lane >> 4, l15 = lane & 15;
    const int col0 = nt * 128 + wn + l15;

    #pragma unroll
    for (int mi = 0; mi < 4; mi++) {
        #pragma unroll
        for (int r = 0; r < 4; r++) {
            int row = mt * 128 + wm + mi * 16 + quad * 4 + r;
            float rl = 1.0f / lsum[b * T + row];
            size_t base = ((size_t)b * T + row) * E + col0;
            #pragma unroll
            for (int ni = 0; ni < 4; ni++)
                out[base + ni * 16] = acc[mi][ni][r] * rl;
        }
    }
}

extern "C" void kernel_launch(void* const* d_in, const int* in_sizes, int n_in,
                              void* d_out, int out_size, void* d_ws, size_t ws_size,
                              hipStream_t stream) {
    const float* q = (const float*)d_in[0];
    const float* k = (const float*)d_in[1];
    const float* v = (const float*)d_in[2];
    float* out = (float*)d_out;

    const size_t QK = (size_t)NB * T * E;
    const size_t PSZ = (size_t)NB * T * T;
    float* lsum = (float*)d_ws;
    unsigned short* qbw = (unsigned short*)((char*)d_ws + 32768);
    unsigned short* kbw = qbw + QK;
    unsigned short* Pw  = kbw + QK;

    const size_t full_need = 32768 + (3 * QK + PSZ) * sizeof(unsigned short);

    if (ws_size >= full_need) {
        unsigned short* vtw = Pw + PSZ;
        prep<<<10272, 256, 0, stream>>>(q, k, v, qbw, kbw, vtw, lsum);
        pass1<<<512, 256, 0, stream>>>(qbw, kbw, Pw, lsum);
        pass2<<<512, 256, 0, stream>>>(Pw, vtw, lsum, out);
    } else {
        unsigned short* vtw = qbw;
        prologue<<<8224, 256, 0, stream>>>(q, k, qbw, kbw, lsum);
        pass1<<<512, 256, 0, stream>>>(qbw, kbw, Pw, lsum);
        v_transpose<<<NB * 64 * 16, 256, 0, stream>>>(v, vtw);
        pass2<<<512, 256, 0, stream>>>(Pw, vtw, lsum, out);
    }
}

// Round 10
// 290.411 us; speedup vs baseline: 1.0419x; 1.0214x over previous
//
#include <hip/hip_runtime.h>

using short8  = __attribute__((ext_vector_type(8))) short;
using ushort8 = __attribute__((ext_vector_type(8))) unsigned short;
using f32x4   = __attribute__((ext_vector_type(4))) float;

#define T 4096
#define E 1024
#define NB 2
#define BM 128
#define BN 128
#define BK 32
#define TILE_ELEMS (BM * BK)     // 4096 ushorts = 8 KB (128-row tile)
#define TILE_A_W   (256 * BK)    // 8192 ushorts = 16 KB (256-row tile)

__device__ __forceinline__ unsigned short f2bf(float f) {
    unsigned int u = __builtin_bit_cast(unsigned int, f);
    u = (u + 0x7FFFu + ((u >> 16) & 1u)) >> 16;
    return (unsigned short)u;
}

__device__ __forceinline__ void gld16(const unsigned short* g, unsigned short* l) {
    __builtin_amdgcn_global_load_lds(
        (__attribute__((address_space(1))) void*)g,
        (__attribute__((address_space(3))) void*)l, 16, 0, 0);
}

// 16 floats/thread (64B/lane loads, 2x ushort8 stores) — 2x the ILP of the
// old 8-elem variant, and used from a 5x-coarser grid.
__device__ __forceinline__ void do_cvt16(const float* __restrict__ src,
                                         unsigned short* __restrict__ dst, int unit) {
    size_t i = ((size_t)unit * 256 + threadIdx.x) * 16;
    float4 f0 = *(const float4*)(src + i);
    float4 f1 = *(const float4*)(src + i + 4);
    float4 f2 = *(const float4*)(src + i + 8);
    float4 f3 = *(const float4*)(src + i + 12);
    ushort8 u0, u1;
    u0[0]=f2bf(f0.x); u0[1]=f2bf(f0.y); u0[2]=f2bf(f0.z); u0[3]=f2bf(f0.w);
    u0[4]=f2bf(f1.x); u0[5]=f2bf(f1.y); u0[6]=f2bf(f1.z); u0[7]=f2bf(f1.w);
    u1[0]=f2bf(f2.x); u1[1]=f2bf(f2.y); u1[2]=f2bf(f2.z); u1[3]=f2bf(f2.w);
    u1[4]=f2bf(f3.x); u1[5]=f2bf(f3.y); u1[6]=f2bf(f3.z); u1[7]=f2bf(f3.w);
    *(ushort8*)(dst + i)     = u0;
    *(ushort8*)(dst + i + 8) = u1;
}

__device__ __forceinline__ void do_vt(const float* __restrict__ v,
                                      unsigned short* __restrict__ vt, int id,
                                      float (*tile)[65]) {
    int b   = id / (64 * 16);
    int rem = id % (64 * 16);
    int t0  = (rem / 16) * 64;
    int e0  = (rem % 16) * 64;
    int tid = threadIdx.x;
    int r   = tid >> 2;
    int c0  = (tid & 3) * 16;
    const float* src = v + ((size_t)(b * T + t0 + r)) * E + e0 + c0;
    #pragma unroll
    for (int i = 0; i < 4; i++) {
        float4 f = *(const float4*)(src + i * 4);
        tile[r][c0 + i*4 + 0] = f.x;
        tile[r][c0 + i*4 + 1] = f.y;
        tile[r][c0 + i*4 + 2] = f.z;
        tile[r][c0 + i*4 + 3] = f.w;
    }
    __syncthreads();
    int er = tid >> 2;
    #pragma unroll
    for (int ch = 0; ch < 2; ch++) {
        int tl = (tid & 3) * 16 + ch * 8;
        ushort8 u;
        #pragma unroll
        for (int j = 0; j < 8; j++) u[j] = f2bf(tile[tl + j][er]);
        *(ushort8*)(vt + ((size_t)(b * E + e0 + er)) * T + t0 + tl) = u;
    }
}

// fused prep, grid 2048: each block converts one q unit (4096 floats), one
// k unit, transposes one 64x64 v tile; blocks <32 zero lsum. ~72 KB traffic
// per block (vs 8 KB in the old 10272-block layout).
__global__ __launch_bounds__(256) void prep(const float* __restrict__ q,
                                            const float* __restrict__ k,
                                            const float* __restrict__ v,
                                            unsigned short* __restrict__ qb,
                                            unsigned short* __restrict__ kb,
                                            unsigned short* __restrict__ vt,
                                            float* __restrict__ lsum) {
    __shared__ float tile[64][65];
    int bid = blockIdx.x;
    do_cvt16(q, qb, bid);
    do_cvt16(k, kb, bid);
    if (bid < 32) lsum[bid * 256 + threadIdx.x] = 0.0f;
    do_vt(v, vt, bid, tile);
}

// fallback pieces (aliased-ws path)
__global__ __launch_bounds__(256) void prologue(const float* __restrict__ q,
                                                const float* __restrict__ k,
                                                unsigned short* __restrict__ qb,
                                                unsigned short* __restrict__ kb,
                                                float* __restrict__ lsum) {
    int bid = blockIdx.x;          // grid 2048
    do_cvt16(q, qb, bid);
    do_cvt16(k, kb, bid);
    if (bid < 32) lsum[bid * 256 + threadIdx.x] = 0.0f;
}
__global__ __launch_bounds__(256) void v_transpose(const float* __restrict__ v,
                                                   unsigned short* __restrict__ vt) {
    __shared__ float tile[64][65];
    do_vt(v, vt, blockIdx.x, tile);
}

// ---------------------------------------------------------------------------
// Pass-2 core: 128x128xBK64, 256 threads (4 waves, 2Mx2N, per-wave 64x64).
// NBUF=2, 64 KB LDS -> 2 blocks/CU. HW-verified R2/R4/R7-R9 (~936 TF as pass2).
// ---------------------------------------------------------------------------
template <int KITERS>
__device__ __forceinline__ void gemm_core64(const unsigned short* Abase, int apitch,
                                            const unsigned short* Bbase, int bpitch,
                                            unsigned short* ldsA, unsigned short* ldsB,
                                            int tid, f32x4 (&acc)[4][4]) {
    constexpr int TILE64 = 128 * 64;         // 8192 ushorts = 16 KB
    const int lane = tid & 63, wave = tid >> 6;
    const int l15 = lane & 15, kq = lane >> 4;
    const int wm = (wave & 1) * 64, wn = (wave >> 1) * 64;

    int goA[4], goB[4], lo[4];
    #pragma unroll
    for (int i = 0; i < 4; i++) {
        int p = i * 256 + tid;
        int r = p >> 3, c = p & 7;
        int sw = c ^ (r & 7);
        goA[i] = r * apitch + sw * 8;
        goB[i] = r * bpitch + sw * 8;
        lo[i] = (i * 256 + wave * 64) * 8;
    }
    int aoff[2][4], boff[2][4];
    #pragma unroll
    for (int mi = 0; mi < 4; mi++) {
        int r = wm + mi * 16 + l15;
        aoff[0][mi] = (r * 8 + (kq ^ (r & 7))) * 8;
        aoff[1][mi] = (r * 8 + ((kq ^ 4) ^ (r & 7))) * 8;
        int rn = wn + mi * 16 + l15;
        boff[0][mi] = (rn * 8 + (kq ^ (rn & 7))) * 8;
        boff[1][mi] = (rn * 8 + ((kq ^ 4) ^ (rn & 7))) * 8;
    }

    #pragma unroll
    for (int i = 0; i < 4; i++) gld16(Abase + goA[i], ldsA + lo[i]);
    #pragma unroll
    for (int i = 0; i < 4; i++) gld16(Bbase + goB[i], ldsB + lo[i]);

    int cbuf = 0;
    for (int kt = 0; kt < KITERS; kt++) {
        int pk = (kt + 1 < KITERS) ? (kt + 1) : 0;
        int ob = cbuf ^ 1;
        asm volatile("s_barrier" ::: "memory");
        #pragma unroll
        for (int i = 0; i < 4; i++) gld16(Abase + goA[i] + pk * 64, ldsA + ob * TILE64 + lo[i]);
        #pragma unroll
        for (int i = 0; i < 4; i++) gld16(Bbase + goB[i] + pk * 64, ldsB + ob * TILE64 + lo[i]);
        asm volatile("s_waitcnt vmcnt(8)" ::: "memory");
        asm volatile("s_barrier" ::: "memory");

        const unsigned short* A = ldsA + cbuf * TILE64;
        const unsigned short* B = ldsB + cbuf * TILE64;
        #pragma unroll
        for (int ks = 0; ks < 2; ks++) {
            short8 af[4], bf[4];
            #pragma unroll
            for (int i = 0; i < 4; i++) {
                af[i] = *(const short8*)(A + aoff[ks][i]);
                bf[i] = *(const short8*)(B + boff[ks][i]);
            }
            #pragma unroll
            for (int mi = 0; mi < 4; mi++)
                #pragma unroll
                for (int ni = 0; ni < 4; ni++)
                    acc[mi][ni] = __builtin_amdgcn_mfma_f32_16x16x32_bf16(af[mi], bf[ni], acc[mi][ni], 0, 0, 0);
        }
        cbuf = ob;
    }
}

// ---------------------------------------------------------------------------
// Pass-1 core: 256x128xBK32, 512 threads, NBUF=2. Measured 85.5 us (R4).
// ---------------------------------------------------------------------------
template <int KITERS>
__device__ __forceinline__ void gemm_core_wide(const unsigned short* Abase, int apitch,
                                               const unsigned short* Bbase, int bpitch,
                                               unsigned short* ldsA, unsigned short* ldsB,
                                               int tid, f32x4 (&acc)[4][4]) {
    const int lane = tid & 63, wave = tid >> 6;          // wave 0..7
    const int l15 = lane & 15, kq = lane >> 4;
    const int wm = (wave & 3) * 64, wn = (wave >> 2) * 64;

    const unsigned short* ga[2];
    int lao[2];
    #pragma unroll
    for (int i = 0; i < 2; i++) {
        int p = i * 512 + tid;                            // A: 1024 chunks
        int r = p >> 2;
        int kqw = (p & 3) ^ ((p >> 3) & 3);
        ga[i] = Abase + (size_t)r * apitch + kqw * 8;
        lao[i] = (i * 512 + wave * 64) * 8;
    }
    const unsigned short* gb;
    int lbo;
    {
        int p = tid;                                      // B: 512 chunks
        int r = p >> 2;
        int kqw = (p & 3) ^ ((p >> 3) & 3);
        gb = Bbase + (size_t)r * bpitch + kqw * 8;
        lbo = (wave * 64) * 8;
    }
    int aoff[4], boff[4];
    #pragma unroll
    for (int mi = 0; mi < 4; mi++) {
        int r = wm + mi * 16 + l15;                       // [0,256)
        aoff[mi] = (r * 4 + (kq ^ ((r >> 1) & 3))) * 8;
        int rn = wn + mi * 16 + l15;                      // [0,128)
        boff[mi] = (rn * 4 + (kq ^ ((rn >> 1) & 3))) * 8;
    }

    // prefetch tile 0 -> buffer 0
    gld16(ga[0], ldsA + lao[0]);
    gld16(ga[1], ldsA + lao[1]);
    gld16(gb,    ldsB + lbo);

    int cbuf = 0;
    for (int kt = 0; kt < KITERS; kt++) {
        int nxt = (kt + 1 < KITERS) ? (kt + 1) : 0;       // tail reload is harmless
        int obuf = cbuf ^ 1;
        asm volatile("s_barrier" ::: "memory");           // done computing on obuf
        gld16(ga[0] + nxt * BK, ldsA + obuf * TILE_A_W + lao[0]);
        gld16(ga[1] + nxt * BK, ldsA + obuf * TILE_A_W + lao[1]);
        gld16(gb    + nxt * BK, ldsB + obuf * TILE_ELEMS + lbo);
        asm volatile("s_waitcnt vmcnt(3)" ::: "memory");  // tile kt landed; kt+1 in flight
        asm volatile("s_barrier" ::: "memory");

        const unsigned short* A = ldsA + cbuf * TILE_A_W;
        const unsigned short* B = ldsB + cbuf * TILE_ELEMS;
        short8 af[4], bf[4];
        #pragma unroll
        for (int i = 0; i < 4; i++) {
            af[i] = *(const short8*)(A + aoff[i]);
            bf[i] = *(const short8*)(B + boff[i]);
        }
        #pragma unroll
        for (int mi = 0; mi < 4; mi++)
            #pragma unroll
            for (int ni = 0; ni < 4; ni++)
                acc[mi][ni] = __builtin_amdgcn_mfma_f32_16x16x32_bf16(af[mi], bf[ni], acc[mi][ni], 0, 0, 0);

        cbuf = obuf;
    }
}

// Pass 1: P = exp2(scale*log2e*(Q K^T) - 12) [bf16], lsum += row sums [fp32]
// 256x128 tile, 512 threads. XCD swizzle: 4 row-tiles x 32 nt per XCD.
__global__ __launch_bounds__(512, 2) void pass1(const unsigned short* __restrict__ qb,
                                                const unsigned short* __restrict__ kb,
                                                unsigned short* __restrict__ P,
                                                float* __restrict__ lsum) {
    __shared__ unsigned short ldsA[2 * TILE_A_W];    // 32 KB
    __shared__ unsigned short ldsB[2 * TILE_ELEMS];  // 16 KB
    const int bx = blockIdx.x;
    const int x = bx & 7, j = bx >> 3;               // j in [0,128)
    const int gm = x * 4 + (j & 3);                  // [0,32): b*16+mt
    const int nt = j >> 2;                           // [0,32)
    const int b = gm >> 4, mt = gm & 15;
    const int tid = threadIdx.x;

    f32x4 acc[4][4];
    #pragma unroll
    for (int i = 0; i < 4; i++)
        #pragma unroll
        for (int jj = 0; jj < 4; jj++) acc[i][jj] = {};

    gemm_core_wide<E / BK>(qb + ((size_t)b * T + mt * 256) * E, E,
                           kb + ((size_t)b * T + nt * BN) * E, E,
                           ldsA, ldsB, tid, acc);

    const int lane = tid & 63, wave = tid >> 6;
    const int wm = (wave & 3) * 64, wn = (wave >> 2) * 64;
    const int quad = lane >> 4, l15 = lane & 15;
    const float sl2 = 0.0625f * 1.44269504089f;
    const int col0 = nt * BN + wn + l15;

    #pragma unroll
    for (int mi = 0; mi < 4; mi++) {
        #pragma unroll
        for (int r = 0; r < 4; r++) {
            int row = mt * 256 + wm + mi * 16 + quad * 4 + r;
            size_t base = ((size_t)b * T + row) * T + col0;
            float s = 0.0f;
            #pragma unroll
            for (int ni = 0; ni < 4; ni++) {
                float p = exp2f(acc[mi][ni][r] * sl2 - 12.0f);
                P[base + ni * 16] = f2bf(p);
                s += p;
            }
            s += __shfl_xor(s, 1);
            s += __shfl_xor(s, 2);
            s += __shfl_xor(s, 4);
            s += __shfl_xor(s, 8);
            if (l15 == 0) atomicAdd(lsum + b * T + row, s);
        }
    }
}

// Pass 2: O = (P @ V) / l ; B operand = VT [b][e][t]
__global__ __launch_bounds__(256, 2) void pass2(const unsigned short* __restrict__ P,
                                                const unsigned short* __restrict__ vt,
                                                const float* __restrict__ lsum,
                                                float* __restrict__ out) {
    constexpr int TILE64 = 128 * 64;
    __shared__ unsigned short ldsA[2 * TILE64];  // 32 KB
    __shared__ unsigned short ldsB[2 * TILE64];  // 32 KB

    const int bx = blockIdx.x;
    const int x = bx & 7, j = bx >> 3;       // j in [0,64)
    const int gm = x * 8 + (j & 7);          // [0,64): b*32+mt
    const int nt = j >> 3;                   // [0,8)
    const int b = gm >> 5, mt = gm & 31;
    const int tid = threadIdx.x;

    f32x4 acc[4][4];
    #pragma unroll
    for (int i = 0; i < 4; i++)
        #pragma unroll
        for (int jj = 0; jj < 4; jj++) acc[i][jj] = {};

    gemm_core64<T / 64>(P + ((size_t)b * T + mt * 128) * T, T,
                        vt + ((size_t)b * E + nt * 128) * T, T,
                        ldsA, ldsB, tid, acc);

    const int lane = tid & 63, wave = tid >> 6;
    const int wm = (wave & 1) * 64, wn = (wave >> 1) * 64;
    const int quad = lane >> 4, l15 = lane & 15;
    const int col0 = nt * 128 + wn + l15;

    #pragma unroll
    for (int mi = 0; mi < 4; mi++) {
        #pragma unroll
        for (int r = 0; r < 4; r++) {
            int row = mt * 128 + wm + mi * 16 + quad * 4 + r;
            float rl = 1.0f / lsum[b * T + row];
            size_t base = ((size_t)b * T + row) * E + col0;
            #pragma unroll
            for (int ni = 0; ni < 4; ni++)
                out[base + ni * 16] = acc[mi][ni][r] * rl;
        }
    }
}

extern "C" void kernel_launch(void* const* d_in, const int* in_sizes, int n_in,
                              void* d_out, int out_size, void* d_ws, size_t ws_size,
                              hipStream_t stream) {
    const float* q = (const float*)d_in[0];
    const float* k = (const float*)d_in[1];
    const float* v = (const float*)d_in[2];
    float* out = (float*)d_out;

    const size_t QK = (size_t)NB * T * E;
    const size_t PSZ = (size_t)NB * T * T;
    float* lsum = (float*)d_ws;
    unsigned short* qbw = (unsigned short*)((char*)d_ws + 32768);
    unsigned short* kbw = qbw + QK;
    unsigned short* Pw  = kbw + QK;

    const size_t full_need = 32768 + (3 * QK + PSZ) * sizeof(unsigned short);

    if (ws_size >= full_need) {
        unsigned short* vtw = Pw + PSZ;
        prep<<<2048, 256, 0, stream>>>(q, k, v, qbw, kbw, vtw, lsum);
        pass1<<<1024, 512, 0, stream>>>(qbw, kbw, Pw, lsum);
        pass2<<<512, 256, 0, stream>>>(Pw, vtw, lsum, out);
    } else {
        unsigned short* vtw = qbw;
        prologue<<<2048, 256, 0, stream>>>(q, k, qbw, kbw, lsum);
        pass1<<<1024, 512, 0, stream>>>(qbw, kbw, Pw, lsum);
        v_transpose<<<NB * 64 * 16, 256, 0, stream>>>(v, vtw);
        pass2<<<512, 256, 0, stream>>>(Pw, vtw, lsum, out);
    }
}

// Round 11
// 284.323 us; speedup vs baseline: 1.0642x; 1.0214x over previous
//
#include <hip/hip_runtime.h>

using short8  = __attribute__((ext_vector_type(8))) short;
using ushort8 = __attribute__((ext_vector_type(8))) unsigned short;
using f32x4   = __attribute__((ext_vector_type(4))) float;

#define T 4096
#define E 1024
#define NB 2
#define BM 128
#define BN 128
#define BK 32
#define TILE_ELEMS (BM * BK)     // 4096 ushorts = 8 KB
#define TILE_A_W   (256 * BK)    // 8192 ushorts = 16 KB

__device__ __forceinline__ unsigned short f2bf(float f) {
    unsigned int u = __builtin_bit_cast(unsigned int, f);
    u = (u + 0x7FFFu + ((u >> 16) & 1u)) >> 16;
    return (unsigned short)u;
}

__device__ __forceinline__ void gld16(const unsigned short* g, unsigned short* l) {
    __builtin_amdgcn_global_load_lds(
        (__attribute__((address_space(1))) void*)g,
        (__attribute__((address_space(3))) void*)l, 16, 0, 0);
}

__device__ __forceinline__ void do_cvt(const float* __restrict__ src,
                                       unsigned short* __restrict__ dst, int blk) {
    size_t i = ((size_t)blk * 256 + threadIdx.x) * 8;
    float4 f0 = *(const float4*)(src + i);
    float4 f1 = *(const float4*)(src + i + 4);
    ushort8 u;
    u[0]=f2bf(f0.x); u[1]=f2bf(f0.y); u[2]=f2bf(f0.z); u[3]=f2bf(f0.w);
    u[4]=f2bf(f1.x); u[5]=f2bf(f1.y); u[6]=f2bf(f1.z); u[7]=f2bf(f1.w);
    *(ushort8*)(dst + i) = u;
}

// v-transpose of one 64x64 tile; tid in [0,256). Caller supplies LDS tile.
__device__ __forceinline__ void do_vt(const float* __restrict__ v,
                                      unsigned short* __restrict__ vt, int id,
                                      float (*tile)[65], int tid) {
    int b   = id / (64 * 16);
    int rem = id % (64 * 16);
    int t0  = (rem / 16) * 64;
    int e0  = (rem % 16) * 64;
    int r   = tid >> 2;
    int c0  = (tid & 3) * 16;
    const float* src = v + ((size_t)(b * T + t0 + r)) * E + e0 + c0;
    #pragma unroll
    for (int i = 0; i < 4; i++) {
        float4 f = *(const float4*)(src + i * 4);
        tile[r][c0 + i*4 + 0] = f.x;
        tile[r][c0 + i*4 + 1] = f.y;
        tile[r][c0 + i*4 + 2] = f.z;
        tile[r][c0 + i*4 + 3] = f.w;
    }
    __syncthreads();
    int er = tid >> 2;
    #pragma unroll
    for (int ch = 0; ch < 2; ch++) {
        int tl = (tid & 3) * 16 + ch * 8;
        ushort8 u;
        #pragma unroll
        for (int j = 0; j < 8; j++) u[j] = f2bf(tile[tl + j][er]);
        *(ushort8*)(vt + ((size_t)(b * E + e0 + er)) * T + t0 + tl) = u;
    }
}

// prep/prologue: [0,4096) q | [4096,8192) k | [8192,8224) zero lsum
__global__ __launch_bounds__(256) void prologue(const float* __restrict__ q,
                                                const float* __restrict__ k,
                                                unsigned short* __restrict__ qb,
                                                unsigned short* __restrict__ kb,
                                                float* __restrict__ lsum) {
    int bid = blockIdx.x;
    if (bid < 4096)      do_cvt(q, qb, bid);
    else if (bid < 8192) do_cvt(k, kb, bid - 4096);
    else                 lsum[(bid - 8192) * 256 + threadIdx.x] = 0.0f;
}
__global__ __launch_bounds__(256) void v_transpose(const float* __restrict__ v,
                                                   unsigned short* __restrict__ vt) {
    __shared__ float tile[64][65];
    do_vt(v, vt, blockIdx.x, tile, threadIdx.x);
}

// ---------------------------------------------------------------------------
// Pass-2 core: 128x128xBK64, 256 threads (4 waves, 2Mx2N). NBUF=2, 64 KB LDS
// -> 2 blocks/CU. HW-verified R2/R4/R7-R10.
// ---------------------------------------------------------------------------
template <int KITERS>
__device__ __forceinline__ void gemm_core64(const unsigned short* Abase, int apitch,
                                            const unsigned short* Bbase, int bpitch,
                                            unsigned short* ldsA, unsigned short* ldsB,
                                            int tid, f32x4 (&acc)[4][4]) {
    constexpr int TILE64 = 128 * 64;         // 8192 ushorts = 16 KB
    const int lane = tid & 63, wave = tid >> 6;
    const int l15 = lane & 15, kq = lane >> 4;
    const int wm = (wave & 1) * 64, wn = (wave >> 1) * 64;

    int goA[4], goB[4], lo[4];
    #pragma unroll
    for (int i = 0; i < 4; i++) {
        int p = i * 256 + tid;
        int r = p >> 3, c = p & 7;
        int sw = c ^ (r & 7);
        goA[i] = r * apitch + sw * 8;
        goB[i] = r * bpitch + sw * 8;
        lo[i] = (i * 256 + wave * 64) * 8;
    }
    int aoff[2][4], boff[2][4];
    #pragma unroll
    for (int mi = 0; mi < 4; mi++) {
        int r = wm + mi * 16 + l15;
        aoff[0][mi] = (r * 8 + (kq ^ (r & 7))) * 8;
        aoff[1][mi] = (r * 8 + ((kq ^ 4) ^ (r & 7))) * 8;
        int rn = wn + mi * 16 + l15;
        boff[0][mi] = (rn * 8 + (kq ^ (rn & 7))) * 8;
        boff[1][mi] = (rn * 8 + ((kq ^ 4) ^ (rn & 7))) * 8;
    }

    #pragma unroll
    for (int i = 0; i < 4; i++) gld16(Abase + goA[i], ldsA + lo[i]);
    #pragma unroll
    for (int i = 0; i < 4; i++) gld16(Bbase + goB[i], ldsB + lo[i]);

    int cbuf = 0;
    for (int kt = 0; kt < KITERS; kt++) {
        int pk = (kt + 1 < KITERS) ? (kt + 1) : 0;
        int ob = cbuf ^ 1;
        asm volatile("s_barrier" ::: "memory");
        #pragma unroll
        for (int i = 0; i < 4; i++) gld16(Abase + goA[i] + pk * 64, ldsA + ob * TILE64 + lo[i]);
        #pragma unroll
        for (int i = 0; i < 4; i++) gld16(Bbase + goB[i] + pk * 64, ldsB + ob * TILE64 + lo[i]);
        asm volatile("s_waitcnt vmcnt(8)" ::: "memory");
        asm volatile("s_barrier" ::: "memory");

        const unsigned short* A = ldsA + cbuf * TILE64;
        const unsigned short* B = ldsB + cbuf * TILE64;
        #pragma unroll
        for (int ks = 0; ks < 2; ks++) {
            short8 af[4], bf[4];
            #pragma unroll
            for (int i = 0; i < 4; i++) {
                af[i] = *(const short8*)(A + aoff[ks][i]);
                bf[i] = *(const short8*)(B + boff[ks][i]);
            }
            #pragma unroll
            for (int mi = 0; mi < 4; mi++)
                #pragma unroll
                for (int ni = 0; ni < 4; ni++)
                    acc[mi][ni] = __builtin_amdgcn_mfma_f32_16x16x32_bf16(af[mi], bf[ni], acc[mi][ni], 0, 0, 0);
        }
        cbuf = ob;
    }
}

// ---------------------------------------------------------------------------
// Pass-1 core: 256x128xBK32, 512 threads, NBUF=2. Measured 85.5 us (R4).
// ---------------------------------------------------------------------------
template <int KITERS>
__device__ __forceinline__ void gemm_core_wide(const unsigned short* Abase, int apitch,
                                               const unsigned short* Bbase, int bpitch,
                                               unsigned short* ldsA, unsigned short* ldsB,
                                               int tid, f32x4 (&acc)[4][4]) {
    const int lane = tid & 63, wave = tid >> 6;          // wave 0..7
    const int l15 = lane & 15, kq = lane >> 4;
    const int wm = (wave & 3) * 64, wn = (wave >> 2) * 64;

    const unsigned short* ga[2];
    int lao[2];
    #pragma unroll
    for (int i = 0; i < 2; i++) {
        int p = i * 512 + tid;                            // A: 1024 chunks
        int r = p >> 2;
        int kqw = (p & 3) ^ ((p >> 3) & 3);
        ga[i] = Abase + (size_t)r * apitch + kqw * 8;
        lao[i] = (i * 512 + wave * 64) * 8;
    }
    const unsigned short* gb;
    int lbo;
    {
        int p = tid;                                      // B: 512 chunks
        int r = p >> 2;
        int kqw = (p & 3) ^ ((p >> 3) & 3);
        gb = Bbase + (size_t)r * bpitch + kqw * 8;
        lbo = (wave * 64) * 8;
    }
    int aoff[4], boff[4];
    #pragma unroll
    for (int mi = 0; mi < 4; mi++) {
        int r = wm + mi * 16 + l15;                       // [0,256)
        aoff[mi] = (r * 4 + (kq ^ ((r >> 1) & 3))) * 8;
        int rn = wn + mi * 16 + l15;                      // [0,128)
        boff[mi] = (rn * 4 + (kq ^ ((rn >> 1) & 3))) * 8;
    }

    gld16(ga[0], ldsA + lao[0]);
    gld16(ga[1], ldsA + lao[1]);
    gld16(gb,    ldsB + lbo);

    int cbuf = 0;
    for (int kt = 0; kt < KITERS; kt++) {
        int nxt = (kt + 1 < KITERS) ? (kt + 1) : 0;
        int obuf = cbuf ^ 1;
        asm volatile("s_barrier" ::: "memory");
        gld16(ga[0] + nxt * BK, ldsA + obuf * TILE_A_W + lao[0]);
        gld16(ga[1] + nxt * BK, ldsA + obuf * TILE_A_W + lao[1]);
        gld16(gb    + nxt * BK, ldsB + obuf * TILE_ELEMS + lbo);
        asm volatile("s_waitcnt vmcnt(3)" ::: "memory");
        asm volatile("s_barrier" ::: "memory");

        const unsigned short* A = ldsA + cbuf * TILE_A_W;
        const unsigned short* B = ldsB + cbuf * TILE_ELEMS;
        short8 af[4], bf[4];
        #pragma unroll
        for (int i = 0; i < 4; i++) {
            af[i] = *(const short8*)(A + aoff[i]);
            bf[i] = *(const short8*)(B + boff[i]);
        }
        #pragma unroll
        for (int mi = 0; mi < 4; mi++)
            #pragma unroll
            for (int ni = 0; ni < 4; ni++)
                acc[mi][ni] = __builtin_amdgcn_mfma_f32_16x16x32_bf16(af[mi], bf[ni], acc[mi][ni], 0, 0, 0);

        cbuf = obuf;
    }
}

// Pass 1: blocks [0,1024): P = exp2(scale*log2e*(Q K^T) - 12), lsum += sums
//         (256x128 tile, identical to R4's measured 85.5 us config).
//         blocks [1024, 1024+NVT): v-transpose, 2 tiles per block (tid<256 /
//         tid>=256) — backfills CU slots as GEMM blocks retire, overlapping
//         vt's 48 MB of traffic with pass1's straggler rounds.
__global__ __launch_bounds__(512, 2) void pass1(const unsigned short* __restrict__ qb,
                                                const unsigned short* __restrict__ kb,
                                                const float* __restrict__ v,
                                                unsigned short* __restrict__ vt,
                                                unsigned short* __restrict__ P,
                                                float* __restrict__ lsum) {
    __shared__ unsigned short lds[2 * TILE_A_W + 2 * TILE_ELEMS];  // 48 KB
    const int bx = blockIdx.x;
    const int tid = threadIdx.x;

    if (bx >= 1024) {   // v-transpose tail blocks (block-uniform branch)
        const int vb = bx - 1024;
        float (*tileA)[65] = (float (*)[65])lds;
        float (*tileB)[65] = (float (*)[65])(lds + 8320);   // 16640 B each
        if (tid < 256) do_vt(v, vt, vb * 2,     tileA, tid);
        else           do_vt(v, vt, vb * 2 + 1, tileB, tid - 256);
        return;
    }

    unsigned short* ldsA = lds;                      // 16384 ushorts
    unsigned short* ldsB = lds + 2 * TILE_A_W;       //  8192 ushorts
    const int x = bx & 7, j = bx >> 3;               // j in [0,128)
    const int gm = x * 4 + (j & 3);                  // [0,32): b*16+mt
    const int nt = j >> 2;                           // [0,32)
    const int b = gm >> 4, mt = gm & 15;

    f32x4 acc[4][4];
    #pragma unroll
    for (int i = 0; i < 4; i++)
        #pragma unroll
        for (int jj = 0; jj < 4; jj++) acc[i][jj] = {};

    gemm_core_wide<E / BK>(qb + ((size_t)b * T + mt * 256) * E, E,
                           kb + ((size_t)b * T + nt * BN) * E, E,
                           ldsA, ldsB, tid, acc);

    const int lane = tid & 63, wave = tid >> 6;
    const int wm = (wave & 3) * 64, wn = (wave >> 2) * 64;
    const int quad = lane >> 4, l15 = lane & 15;
    const float sl2 = 0.0625f * 1.44269504089f;
    const int col0 = nt * BN + wn + l15;

    #pragma unroll
    for (int mi = 0; mi < 4; mi++) {
        #pragma unroll
        for (int r = 0; r < 4; r++) {
            int row = mt * 256 + wm + mi * 16 + quad * 4 + r;
            size_t base = ((size_t)b * T + row) * T + col0;
            float s = 0.0f;
            #pragma unroll
            for (int ni = 0; ni < 4; ni++) {
                float p = exp2f(acc[mi][ni][r] * sl2 - 12.0f);
                P[base + ni * 16] = f2bf(p);
                s += p;
            }
            s += __shfl_xor(s, 1);
            s += __shfl_xor(s, 2);
            s += __shfl_xor(s, 4);
            s += __shfl_xor(s, 8);
            if (l15 == 0) atomicAdd(lsum + b * T + row, s);
        }
    }
}

// Pass 2: O = (P @ V) / l ; B operand = VT [b][e][t]  (R4 exact)
__global__ __launch_bounds__(256, 2) void pass2(const unsigned short* __restrict__ P,
                                                const unsigned short* __restrict__ vt,
                                                const float* __restrict__ lsum,
                                                float* __restrict__ out) {
    constexpr int TILE64 = 128 * 64;
    __shared__ unsigned short ldsA[2 * TILE64];  // 32 KB
    __shared__ unsigned short ldsB[2 * TILE64];  // 32 KB

    const int bx = blockIdx.x;
    const int x = bx & 7, j = bx >> 3;       // j in [0,64)
    const int gm = x * 8 + (j & 7);          // [0,64): b*32+mt
    const int nt = j >> 3;                   // [0,8)
    const int b = gm >> 5, mt = gm & 31;
    const int tid = threadIdx.x;

    f32x4 acc[4][4];
    #pragma unroll
    for (int i = 0; i < 4; i++)
        #pragma unroll
        for (int jj = 0; jj < 4; jj++) acc[i][jj] = {};

    gemm_core64<T / 64>(P + ((size_t)b * T + mt * 128) * T, T,
                        vt + ((size_t)b * E + nt * 128) * T, T,
                        ldsA, ldsB, tid, acc);

    const int lane = tid & 63, wave = tid >> 6;
    const int wm = (wave & 1) * 64, wn = (wave >> 1) * 64;
    const int quad = lane >> 4, l15 = lane & 15;
    const int col0 = nt * 128 + wn + l15;

    #pragma unroll
    for (int mi = 0; mi < 4; mi++) {
        #pragma unroll
        for (int r = 0; r < 4; r++) {
            int row = mt * 128 + wm + mi * 16 + quad * 4 + r;
            float rl = 1.0f / lsum[b * T + row];
            size_t base = ((size_t)b * T + row) * E + col0;
            #pragma unroll
            for (int ni = 0; ni < 4; ni++)
                out[base + ni * 16] = acc[mi][ni][r] * rl;
        }
    }
}

extern "C" void kernel_launch(void* const* d_in, const int* in_sizes, int n_in,
                              void* d_out, int out_size, void* d_ws, size_t ws_size,
                              hipStream_t stream) {
    const float* q = (const float*)d_in[0];
    const float* k = (const float*)d_in[1];
    const float* v = (const float*)d_in[2];
    float* out = (float*)d_out;

    const size_t QK = (size_t)NB * T * E;
    const size_t PSZ = (size_t)NB * T * T;
    float* lsum = (float*)d_ws;
    unsigned short* qbw = (unsigned short*)((char*)d_ws + 32768);
    unsigned short* kbw = qbw + QK;
    unsigned short* Pw  = kbw + QK;

    const size_t full_need = 32768 + (3 * QK + PSZ) * sizeof(unsigned short);

    if (ws_size >= full_need) {
        unsigned short* vtw = Pw + PSZ;
        prologue<<<8224, 256, 0, stream>>>(q, k, qbw, kbw, lsum);
        pass1<<<1024 + 1024, 512, 0, stream>>>(qbw, kbw, v, vtw, Pw, lsum);
        pass2<<<512, 256, 0, stream>>>(Pw, vtw, lsum, out);
    } else {
        // vt aliases qbw: cannot overlap vt with pass1's qb reads ->
        // keep the separate serial v_transpose kernel here.
        unsigned short* vtw = qbw;
        prologue<<<8224, 256, 0, stream>>>(q, k, qbw, kbw, lsum);
        pass1<<<1024, 512, 0, stream>>>(qbw, kbw, v, vtw, Pw, lsum);
        v_transpose<<<NB * 64 * 16, 256, 0, stream>>>(v, vtw);
        pass2<<<512, 256, 0, stream>>>(Pw, vtw, lsum, out);
    }
}